// Round 12
// baseline (1118.602 us; speedup 1.0000x reference)
//
#include <hip/hip_runtime.h>
#include <cstddef>

#define HID 128
#define NGRAPH 256
#define KIT 5
#define BCAP 64
#define BN_EPS 1e-5f
#define BKCHUNK 2048
#define SBPAD 36   // sbuf row stride in ints (144B: int4-aligned, 9-bank offset)

typedef __attribute__((ext_vector_type(8))) short  short8v;
typedef __attribute__((ext_vector_type(8))) unsigned short ushort8v;
typedef __attribute__((ext_vector_type(4))) float  float4v;

__device__ __forceinline__ unsigned short f2b(float f) {
    unsigned int u = __float_as_uint(f);
    u = (u + 0x7FFFu + ((u >> 16) & 1u)) >> 16;
    return (unsigned short)u;
}
__device__ __forceinline__ float b2f(unsigned short b) {
    return __uint_as_float(((unsigned int)b) << 16);
}
__device__ __forceinline__ int uminc(int v, int hi) {   // clamp via unsigned min
    return (int)min((unsigned)v, (unsigned)hi);
}

// BN finalize, done redundantly per block: ssS[c]=scale, ssS[128+c]=shift
__device__ __forceinline__ void compute_ss(const float* __restrict__ st,
                                           const float* __restrict__ g,
                                           const float* __restrict__ be,
                                           float* ssS, int M, int t) {
    if (t < HID) {
        float invM = 1.f / (float)M;
        float m = st[t] * invM;
        float v = fmaxf(st[HID + t] * invM - m * m, 0.f);
        float sc = rsqrtf(v + BN_EPS) * g[t];
        ssS[t] = sc;
        ssS[HID + t] = fmaf(-m, sc, be[t]);
    }
}

// ---- bucket build, XCD-region-sliced, int4-vectorized edge reads ----
__global__ __launch_bounds__(256) void k_bucket(const int* __restrict__ esrc,
                                                const int* __restrict__ edst,
                                                int* __restrict__ cnt,
                                                int* __restrict__ bucket,
                                                int E, int rdiv) {
    const int region = blockIdx.x & 7;
    const int base4 = (blockIdx.x >> 3) * (BKCHUNK / 4);
    for (int i = threadIdx.x; i < BKCHUNK / 4; i += 256) {
        const int e4 = base4 + i;
        const int e0 = e4 * 4;
        if (e0 >= E) break;
        const int4 d4 = ((const int4*)edst)[e4];
        const int4 s4 = ((const int4*)esrc)[e4];
        const int dd[4] = {d4.x, d4.y, d4.z, d4.w};
        const int ss[4] = {s4.x, s4.y, s4.z, s4.w};
#pragma unroll
        for (int u = 0; u < 4; ++u) {
            if (e0 + u < E && dd[u] / rdiv == region) {
                const int slot = atomicAdd(cnt + dd[u], 1);
                if (slot < BCAP) bucket[(size_t)dd[u] * BCAP + slot] = ss[u];
            }
        }
    }
}

// ---- merged prep: [X->bf16 | W1/W2 transpose->bf16 | zero rows N of Xb,h2b] ----
__global__ __launch_bounds__(256) void k_prep(const float* __restrict__ X,
                                              const float* __restrict__ W1,
                                              const float* __restrict__ W2,
                                              unsigned short* __restrict__ Xb,
                                              unsigned short* __restrict__ Wt1,
                                              unsigned short* __restrict__ Wt2,
                                              unsigned short* __restrict__ h2b,
                                              int n8, int nx, int N) {
    const int bid = blockIdx.x;
    if (bid < nx) {
        const int i = bid * 256 + threadIdx.x;
        if (i >= n8) return;
        const float4v v0 = ((const float4v*)X)[i * 2];
        const float4v v1 = ((const float4v*)X)[i * 2 + 1];
        ushort8v pk;
#pragma unroll
        for (int q = 0; q < 4; ++q) { pk[q] = f2b(v0[q]); pk[q + 4] = f2b(v1[q]); }
        ((ushort8v*)Xb)[i] = pk;
    } else if (bid < nx + 2 * KIT) {
        const int m = bid - nx;
        const float* w = (m < KIT) ? W1 + (size_t)m * HID * HID
                                   : W2 + (size_t)(m - KIT) * HID * HID;
        unsigned short* wt = (m < KIT) ? Wt1 + (size_t)m * HID * HID
                                       : Wt2 + (size_t)(m - KIT) * HID * HID;
        for (int idx = threadIdx.x; idx < HID * HID; idx += 256) {
            int k = idx >> 7, n = idx & 127;
            wt[n * HID + k] = f2b(w[k * HID + n]);
        }
    } else {
        if (threadIdx.x < HID) {
            Xb[(size_t)N * HID + threadIdx.x] = 0;
            h2b[(size_t)N * HID + threadIdx.x] = 0;
        }
    }
}

// ---- fused layer1: [pure-sum gather of pre-transformed h -> GEMM1 -> stats1] ----
__global__ __launch_bounds__(256, 6) void k_layer1(const unsigned short* __restrict__ H,
                                                   const int* __restrict__ cnt,
                                                   const int* __restrict__ bucket,
                                                   const unsigned short* __restrict__ Wt,
                                                   const float* __restrict__ bias,
                                                   unsigned short* __restrict__ Out,
                                                   float* __restrict__ stats, int N) {
    __shared__ float csum[HID], csq[HID];
    __shared__ int sbuf[4][16][SBPAD];        // [wave][row][slot 0..31]; slot0 = self
    __shared__ unsigned short As[64 * HID];   // bf16 agg rows, XOR-swizzled
    const int t = threadIdx.x;
    if (t < HID) { csum[t] = 0.f; csq[t] = 0.f; }

    const int wave = t >> 6, lane = t & 63;
    const int r0w = blockIdx.x * 64 + wave * 16;
    char* Abase = (char*)As + wave * 16 * 256;

    int cnt16 = 0;
    if (lane < 16) cnt16 = cnt[uminc(r0w + lane, N - 1)];
#pragma unroll
    for (int rr = 0; rr < 16; ++rr) {
        const int rowc = uminc(r0w + rr, N - 1);
        if (lane < 31)       sbuf[wave][rr][lane + 1] = bucket[(size_t)rowc * BCAP + lane];
        else if (lane == 63) sbuf[wave][rr][0] = rowc;
    }
    __syncthreads();

    // ------------------ phase 1: gather (pure adds, row-parallel, 8-deep) ----------
    {
        const int g  = lane >> 4;    // row group 0..3
        const int cl = lane & 15;    // col lane: cols cl*8 .. cl*8+7
        for (int rb = 0; rb < 4; ++rb) {
            const int rr = rb * 4 + g;
            const int rowc = uminc(r0w + rr, N - 1);
            const int deg = min(__shfl(cnt16, rr), 63);
            const int T = deg + 1;               // terms incl. self (slot 0)
            const int* spL = &sbuf[wave][rr][0];
            const int* spG = bucket + (size_t)rowc * BCAP;
            float a[8];
#pragma unroll
            for (int q = 0; q < 8; ++q) a[q] = 0.f;
            const int nSt = (T + 7) >> 3;
            for (int st = 0; st < nSt; ++st) {
                const int base = st * 8;
                int sid[8];
                if (base < 32) {
                    const int4 s4a = *(const int4*)(spL + base);
                    const int4 s4b = *(const int4*)(spL + base + 4);
                    sid[0] = s4a.x; sid[1] = s4a.y; sid[2] = s4a.z; sid[3] = s4a.w;
                    sid[4] = s4b.x; sid[5] = s4b.y; sid[6] = s4b.z; sid[7] = s4b.w;
                } else {
#pragma unroll
                    for (int u = 0; u < 8; ++u)
                        sid[u] = spG[uminc(base + u - 1, BCAP - 1)];
                }
                ushort8v v[8];
#pragma unroll
                for (int u = 0; u < 8; ++u) {
                    const int s = base + u;
                    int src = (s == 0) ? rowc : uminc(sid[u], N - 1);
                    src = (s < T) ? src : N;      // zero row for masked slots
                    v[u] = *(const ushort8v*)(H + (size_t)src * HID + cl * 8);
                }
#pragma unroll
                for (int u = 0; u < 8; ++u)
#pragma unroll
                    for (int q = 0; q < 8; ++q)
                        a[q] += b2f(v[u][q]);
            }
            ushort8v pk;
#pragma unroll
            for (int q = 0; q < 8; ++q) pk[q] = f2b(a[q]);
            const int byt = (rr * 256 + cl * 16) ^ ((rr & 7) << 4);
            *(ushort8v*)(Abase + byt) = pk;
        }
    }

    // ------------------ phase 2: GEMM from LDS ------------------
    const int lr = lane & 15, lk = lane >> 4;
    const int r0 = r0w;
    short8v af[4];
#pragma unroll
    for (int kb = 0; kb < 4; ++kb) {
        const int byt = (lr * 256 + kb * 64 + lk * 16) ^ ((lr & 7) << 4);
        af[kb] = *(const short8v*)(Abase + byt);
    }
    float4v acc[8];
#pragma unroll
    for (int ct = 0; ct < 8; ++ct) {
        float4v c = {0.f, 0.f, 0.f, 0.f};
        const unsigned short* bw = Wt + (size_t)(ct * 16 + lr) * HID + lk * 8;
#pragma unroll
        for (int kb = 0; kb < 4; ++kb) {
            short8v bf = *reinterpret_cast<const short8v*>(bw + kb * 32);
            c = __builtin_amdgcn_mfma_f32_16x16x32_bf16(af[kb], bf, c, 0, 0, 0);
        }
        acc[ct] = c;
    }

#pragma unroll
    for (int ct = 0; ct < 8; ++ct) {
        const int col = ct * 16 + lr;
        const float b = bias[col];
        float s = 0.f, q = 0.f;
#pragma unroll
        for (int j = 0; j < 4; ++j) {
            const int row = r0 + lk * 4 + j;
            if (row < N) {
                const float o = acc[ct][j] + b;
                Out[(size_t)row * HID + col] = f2b(o);
                s += o; q += o * o;
            }
        }
        s += __shfl_xor(s, 16); s += __shfl_xor(s, 32);
        q += __shfl_xor(q, 16); q += __shfl_xor(q, 32);
        if (lk == 0) { atomicAdd(&csum[col], s); atomicAdd(&csq[col], q); }
    }
    __syncthreads();
    if (t < HID) {
        atomicAdd(stats + t, csum[t]);
        atomicAdd(stats + HID + t, csq[t]);
    }
}

// ---- layer2 v3: 256 rows/block, 2-stage software pipeline (load t+1 || compute t)
__global__ __launch_bounds__(256) void k_layer2(const unsigned short* __restrict__ A,
                                                const float* __restrict__ st_in,
                                                const float* __restrict__ g_in,
                                                const float* __restrict__ be_in,
                                                const unsigned short* __restrict__ Wt,
                                                const float* __restrict__ bias,
                                                unsigned short* __restrict__ Out,
                                                float* __restrict__ stats, int M) {
    __shared__ float ssS[2 * HID];
    __shared__ float csum[HID], csq[HID];
    const int t = threadIdx.x;
    if (t < HID) { csum[t] = 0.f; csq[t] = 0.f; }
    compute_ss(st_in, g_in, be_in, ssS, M, t);
    __syncthreads();

    const int wave = t >> 6, lane = t & 63;
    const int lr = lane & 15, lk = lane >> 4;

    const float4v sc0[4] = {*(const float4v*)&ssS[lk * 8],
                            *(const float4v*)&ssS[32 + lk * 8],
                            *(const float4v*)&ssS[64 + lk * 8],
                            *(const float4v*)&ssS[96 + lk * 8]};
    const float4v sc1[4] = {*(const float4v*)&ssS[lk * 8 + 4],
                            *(const float4v*)&ssS[32 + lk * 8 + 4],
                            *(const float4v*)&ssS[64 + lk * 8 + 4],
                            *(const float4v*)&ssS[96 + lk * 8 + 4]};
    const float4v sh0[4] = {*(const float4v*)&ssS[HID + lk * 8],
                            *(const float4v*)&ssS[HID + 32 + lk * 8],
                            *(const float4v*)&ssS[HID + 64 + lk * 8],
                            *(const float4v*)&ssS[HID + 96 + lk * 8]};
    const float4v sh1[4] = {*(const float4v*)&ssS[HID + lk * 8 + 4],
                            *(const float4v*)&ssS[HID + 32 + lk * 8 + 4],
                            *(const float4v*)&ssS[HID + 64 + lk * 8 + 4],
                            *(const float4v*)&ssS[HID + 96 + lk * 8 + 4]};

    auto load_tile = [&](int tt, ushort8v* dst) {
        const int arow = blockIdx.x * 256 + tt * 64 + wave * 16 + lr;
        const unsigned short* ap = A + (size_t)arow * HID + lk * 8;
        const bool rowok = arow < M;
#pragma unroll
        for (int kb = 0; kb < 4; ++kb) {
            if (rowok) dst[kb] = *reinterpret_cast<const ushort8v*>(ap + kb * 32);
            else       dst[kb] = (ushort8v)(unsigned short)0;
        }
    };

    ushort8v stage[4];
    load_tile(0, stage);

#pragma unroll
    for (int tt = 0; tt < 4; ++tt) {
        ushort8v nxt[4];
        if (tt < 3) load_tile(tt + 1, nxt);

        const int r0 = blockIdx.x * 256 + tt * 64 + wave * 16;
        short8v af[4];
#pragma unroll
        for (int kb = 0; kb < 4; ++kb) {
            ushort8v pk;
#pragma unroll
            for (int j = 0; j < 4; ++j) {
                pk[j]     = f2b(fmaxf(fmaf(b2f(stage[kb][j]),     sc0[kb][j], sh0[kb][j]), 0.f));
                pk[j + 4] = f2b(fmaxf(fmaf(b2f(stage[kb][j + 4]), sc1[kb][j], sh1[kb][j]), 0.f));
            }
            af[kb] = *reinterpret_cast<short8v*>(&pk);
        }

        float4v acc[8];
#pragma unroll
        for (int ct = 0; ct < 8; ++ct) {
            float4v c = {0.f, 0.f, 0.f, 0.f};
            const unsigned short* bw = Wt + (size_t)(ct * 16 + lr) * HID + lk * 8;
#pragma unroll
            for (int kb = 0; kb < 4; ++kb) {
                short8v bf = *reinterpret_cast<const short8v*>(bw + kb * 32);
                c = __builtin_amdgcn_mfma_f32_16x16x32_bf16(af[kb], bf, c, 0, 0, 0);
            }
            acc[ct] = c;
        }

#pragma unroll
        for (int ct = 0; ct < 8; ++ct) {
            const int col = ct * 16 + lr;
            const float b = bias[col];
            float s = 0.f, q = 0.f;
#pragma unroll
            for (int j = 0; j < 4; ++j) {
                const int row = r0 + lk * 4 + j;
                if (row < M) {
                    const float o = acc[ct][j] + b;
                    Out[(size_t)row * HID + col] = f2b(o);
                    s += o; q += o * o;
                }
            }
            s += __shfl_xor(s, 16); s += __shfl_xor(s, 32);
            q += __shfl_xor(q, 16); q += __shfl_xor(q, 32);
            if (lk == 0) { atomicAdd(&csum[col], s); atomicAdd(&csq[col], q); }
        }
#pragma unroll
        for (int kb = 0; kb < 4; ++kb) stage[kb] = nxt[kb];
    }
    __syncthreads();
    if (t < HID) {
        atomicAdd(stats + t, csum[t]);
        atomicAdd(stats + HID + t, csq[t]);
    }
}

// ---- pool+writeback v2: vectorized streaming; 16 rows in flight; LDS reduce ----
__global__ __launch_bounds__(256) void k_pool(const unsigned short* __restrict__ p2,
                                              const float* __restrict__ st,
                                              const float* __restrict__ g,
                                              const float* __restrict__ be,
                                              const int* __restrict__ batch,
                                              int N, float* __restrict__ feats, int it,
                                              unsigned short* __restrict__ hout) {
    __shared__ float ssS[2 * HID];
    __shared__ float red[16 * (HID + 4)];
    const int t = threadIdx.x;
    compute_ss(st, g, be, ssS, N, t);
    __syncthreads();
    const int gph = blockIdx.x;
    int a = 0, b = N;
    while (a < b) { int m = (a + b) >> 1; if (batch[m] < gph) a = m + 1; else b = m; }
    const int lo = a;
    b = N;
    while (a < b) { int m = (a + b) >> 1; if (batch[m] < gph + 1) a = m + 1; else b = m; }
    const int hi = a;
    const int len = hi - lo;
    const int q0 = lo + (int)(((long long)len * blockIdx.y) >> 2);
    const int q1 = lo + (int)(((long long)len * (blockIdx.y + 1)) >> 2);

    const int rl = t >> 4;          // row lane 0..15
    const int cs = t & 15;          // col slice: cols cs*8 .. cs*8+7
    float sc[8], sh[8];
#pragma unroll
    for (int q = 0; q < 8; ++q) { sc[q] = ssS[cs * 8 + q]; sh[q] = ssS[HID + cs * 8 + q]; }

    float acc[8];
#pragma unroll
    for (int q = 0; q < 8; ++q) acc[q] = 0.f;
    for (int r = q0 + rl; r < q1; r += 16) {
        const ushort8v raw = *(const ushort8v*)(p2 + (size_t)r * HID + cs * 8);
        ushort8v pk;
#pragma unroll
        for (int q = 0; q < 8; ++q) {
            const float hv = fmaxf(fmaf(b2f(raw[q]), sc[q], sh[q]), 0.f);
            pk[q] = f2b(hv);
            acc[q] += hv;
        }
        *(ushort8v*)(hout + (size_t)r * HID + cs * 8) = pk;
    }
#pragma unroll
    for (int q = 0; q < 8; ++q) red[rl * (HID + 4) + cs * 8 + q] = acc[q];
    __syncthreads();
    if (t < HID) {
        float s = 0.f;
#pragma unroll
        for (int i = 0; i < 16; ++i) s += red[i * (HID + 4) + t];
        atomicAdd(feats + (size_t)gph * (KIT * HID) + it * HID + t, s);
    }
}

// ---------------- fused head: out = relu(feats@Wh1+bh1)@Wh2 + bh2 ---------------
__global__ __launch_bounds__(KIT * HID) void k_head(const float* __restrict__ feats,
                                                    const float* __restrict__ Wh1,
                                                    const float* __restrict__ bh1,
                                                    const float* __restrict__ Wh2,
                                                    const float* __restrict__ bh2,
                                                    float* __restrict__ out) {
    __shared__ float fr[KIT * HID];
    __shared__ float z1s[KIT * HID];
    const int r = blockIdx.x;
    const int c = threadIdx.x;
    fr[c] = feats[r * (KIT * HID) + c];
    __syncthreads();
    float acc = bh1[c];
    for (int k = 0; k < KIT * HID; ++k) acc = fmaf(fr[k], Wh1[k * (KIT * HID) + c], acc);
    z1s[c] = fmaxf(acc, 0.f);
    __syncthreads();
    if (c < 10) {
        float s = bh2[c];
        for (int k = 0; k < KIT * HID; ++k) s = fmaf(z1s[k], Wh2[k * 10 + c], s);
        out[r * 10 + c] = s;
    }
}

extern "C" void kernel_launch(void* const* d_in, const int* in_sizes, int n_in,
                              void* d_out, int out_size, void* d_ws, size_t ws_size,
                              hipStream_t stream) {
    const float* X   = (const float*)d_in[0];
    const float* W1  = (const float*)d_in[1];
    const float* b1  = (const float*)d_in[2];
    const float* g1  = (const float*)d_in[3];
    const float* be1 = (const float*)d_in[4];
    const float* W2  = (const float*)d_in[5];
    const float* b2  = (const float*)d_in[6];
    const float* g2  = (const float*)d_in[7];
    const float* be2 = (const float*)d_in[8];
    const float* Wh1 = (const float*)d_in[9];
    const float* bh1 = (const float*)d_in[10];
    const float* Wh2 = (const float*)d_in[11];
    const float* bh2 = (const float*)d_in[12];
    const int* esrc  = (const int*)d_in[13];
    const int* edst  = (const int*)d_in[14];
    const int* batch = (const int*)d_in[15];
    float* out = (float*)d_out;

    const int N = in_sizes[0] / HID;
    const int E = in_sizes[13];

    char* w = (char*)d_ws;
    size_t off = 0;
    auto alloc = [&](size_t bytes) {
        void* p = w + off;
        off += (bytes + 255) & ~(size_t)255;
        return p;
    };
    // zero-init block first (cnt, stats, feats contiguous -> ONE memset)
    int*   cnt    = (int*)alloc((size_t)N * 4);
    float* stats  = (float*)alloc((size_t)2 * KIT * 2 * HID * 4);
    float* feats  = (float*)alloc((size_t)NGRAPH * KIT * HID * 4);
    const size_t zero_span = off;
    unsigned short* Xb   = (unsigned short*)alloc((size_t)(N + 1) * HID * 2);  // row N = 0
    unsigned short* h2b  = (unsigned short*)alloc((size_t)(N + 1) * HID * 2);  // row N = 0
    unsigned short* p1b  = (unsigned short*)alloc((size_t)N * HID * 2);
    unsigned short* p2b  = (unsigned short*)alloc((size_t)N * HID * 2);
    unsigned short* Wt1  = (unsigned short*)alloc((size_t)KIT * HID * HID * 2);
    unsigned short* Wt2  = (unsigned short*)alloc((size_t)KIT * HID * HID * 2);
    int*   bucket = (int*)alloc((size_t)N * BCAP * 4);

    hipMemsetAsync(w, 0, zero_span, stream);

    const int rdiv = (N + 7) / 8;
    const int nchunk = (E + BKCHUNK - 1) / BKCHUNK;
    k_bucket<<<nchunk * 8, 256, 0, stream>>>(esrc, edst, cnt, bucket, E, rdiv);

    const int n8 = N * (HID / 8);
    const int nx = (n8 + 255) / 256;
    k_prep<<<nx + 2 * KIT + 1, 256, 0, stream>>>(X, W1, W2, Xb, Wt1, Wt2, h2b, n8, nx, N);

    const int g1grid = (N + 63) / 64;
    const int g2grid = (N + 255) / 256;
    for (int i = 0; i < KIT; ++i) {
        float* st1 = stats + (size_t)(2 * i) * 256;
        float* st2 = stats + (size_t)(2 * i + 1) * 256;
        const unsigned short* hin = (i == 0) ? Xb : h2b;

        k_layer1<<<g1grid, 256, 0, stream>>>(
            hin, cnt, bucket, Wt1 + (size_t)i * HID * HID, b1 + i * HID, p1b, st1, N);
        k_layer2<<<g2grid, 256, 0, stream>>>(
            p1b, st1, g1 + i * HID, be1 + i * HID,
            Wt2 + (size_t)i * HID * HID, b2 + i * HID, p2b, st2, N);
        k_pool<<<dim3(NGRAPH, 4), 256, 0, stream>>>(
            p2b, st2, g2 + i * HID, be2 + i * HID, batch, N, feats, i, h2b);
    }
    k_head<<<NGRAPH, KIT * HID, 0, stream>>>(feats, Wh1, bh1, Wh2, bh2, out);
}

// Round 13
// 1083.016 us; speedup vs baseline: 1.0329x; 1.0329x over previous
//
#include <hip/hip_runtime.h>
#include <cstddef>

#define HID 128
#define NGRAPH 256
#define KIT 5
#define BCAP 64
#define BN_EPS 1e-5f
#define BKCHUNK 2048
#define SBPAD 36   // sbuf row stride in ints (144B: int4-aligned, 9-bank offset)

typedef __attribute__((ext_vector_type(8))) short  short8v;
typedef __attribute__((ext_vector_type(8))) unsigned short ushort8v;
typedef __attribute__((ext_vector_type(4))) float  float4v;

__device__ __forceinline__ unsigned short f2b(float f) {
    unsigned int u = __float_as_uint(f);
    u = (u + 0x7FFFu + ((u >> 16) & 1u)) >> 16;
    return (unsigned short)u;
}
__device__ __forceinline__ float b2f(unsigned short b) {
    return __uint_as_float(((unsigned int)b) << 16);
}
__device__ __forceinline__ int uminc(int v, int hi) {   // clamp via unsigned min
    return (int)min((unsigned)v, (unsigned)hi);
}

// BN finalize, done redundantly per block: ssS[c]=scale, ssS[128+c]=shift
__device__ __forceinline__ void compute_ss(const float* __restrict__ st,
                                           const float* __restrict__ g,
                                           const float* __restrict__ be,
                                           float* ssS, int M, int t) {
    if (t < HID) {
        float invM = 1.f / (float)M;
        float m = st[t] * invM;
        float v = fmaxf(st[HID + t] * invM - m * m, 0.f);
        float sc = rsqrtf(v + BN_EPS) * g[t];
        ssS[t] = sc;
        ssS[HID + t] = fmaf(-m, sc, be[t]);
    }
}

// ---- bucket build, XCD-region-sliced: grid (8 * nchunk); region = bid & 7 ----
__global__ __launch_bounds__(256) void k_bucket(const int* __restrict__ esrc,
                                                const int* __restrict__ edst,
                                                int* __restrict__ cnt,
                                                int* __restrict__ bucket,
                                                int E, int rdiv) {
    const int region = blockIdx.x & 7;
    const int base = (blockIdx.x >> 3) * BKCHUNK;
    for (int i = threadIdx.x; i < BKCHUNK; i += 256) {
        const int e = base + i;
        if (e >= E) break;
        const int d = edst[e];
        if (d / rdiv == region) {
            const int slot = atomicAdd(cnt + d, 1);
            if (slot < BCAP) bucket[(size_t)d * BCAP + slot] = esrc[e];
        }
    }
}

// ---- merged prep: [X->bf16 | W1/W2 transpose->bf16 | zero rows N of Xb,h2b] ----
__global__ __launch_bounds__(256) void k_prep(const float* __restrict__ X,
                                              const float* __restrict__ W1,
                                              const float* __restrict__ W2,
                                              unsigned short* __restrict__ Xb,
                                              unsigned short* __restrict__ Wt1,
                                              unsigned short* __restrict__ Wt2,
                                              unsigned short* __restrict__ h2b,
                                              int n8, int nx, int N) {
    const int bid = blockIdx.x;
    if (bid < nx) {
        const int i = bid * 256 + threadIdx.x;
        if (i >= n8) return;
        const float4v v0 = ((const float4v*)X)[i * 2];
        const float4v v1 = ((const float4v*)X)[i * 2 + 1];
        ushort8v pk;
#pragma unroll
        for (int q = 0; q < 4; ++q) { pk[q] = f2b(v0[q]); pk[q + 4] = f2b(v1[q]); }
        ((ushort8v*)Xb)[i] = pk;
    } else if (bid < nx + 2 * KIT) {
        const int m = bid - nx;
        const float* w = (m < KIT) ? W1 + (size_t)m * HID * HID
                                   : W2 + (size_t)(m - KIT) * HID * HID;
        unsigned short* wt = (m < KIT) ? Wt1 + (size_t)m * HID * HID
                                       : Wt2 + (size_t)(m - KIT) * HID * HID;
        for (int idx = threadIdx.x; idx < HID * HID; idx += 256) {
            int k = idx >> 7, n = idx & 127;
            wt[n * HID + k] = f2b(w[k * HID + n]);
        }
    } else {
        if (threadIdx.x < HID) {
            Xb[(size_t)N * HID + threadIdx.x] = 0;
            h2b[(size_t)N * HID + threadIdx.x] = 0;
        }
    }
}

// ---- fused layer1: [pure-sum gather of pre-transformed h -> GEMM1 -> stats1] ----
__global__ __launch_bounds__(256, 6) void k_layer1(const unsigned short* __restrict__ H,
                                                   const int* __restrict__ cnt,
                                                   const int* __restrict__ bucket,
                                                   const unsigned short* __restrict__ Wt,
                                                   const float* __restrict__ bias,
                                                   unsigned short* __restrict__ Out,
                                                   float* __restrict__ stats, int N) {
    __shared__ float csum[HID], csq[HID];
    __shared__ int sbuf[4][16][SBPAD];        // [wave][row][slot 0..31]; slot0 = self
    __shared__ unsigned short As[64 * HID];   // bf16 agg rows, XOR-swizzled
    const int t = threadIdx.x;
    if (t < HID) { csum[t] = 0.f; csq[t] = 0.f; }

    const int wave = t >> 6, lane = t & 63;
    const int r0w = blockIdx.x * 64 + wave * 16;
    char* Abase = (char*)As + wave * 16 * 256;

    int cnt16 = 0;
    if (lane < 16) cnt16 = cnt[uminc(r0w + lane, N - 1)];
#pragma unroll
    for (int rr = 0; rr < 16; ++rr) {
        const int rowc = uminc(r0w + rr, N - 1);
        if (lane < 31)       sbuf[wave][rr][lane + 1] = bucket[(size_t)rowc * BCAP + lane];
        else if (lane == 63) sbuf[wave][rr][0] = rowc;
    }
    __syncthreads();

    // ------------------ phase 1: gather (pure adds, row-parallel, 8-deep) ----------
    {
        const int g  = lane >> 4;    // row group 0..3
        const int cl = lane & 15;    // col lane: cols cl*8 .. cl*8+7
        for (int rb = 0; rb < 4; ++rb) {
            const int rr = rb * 4 + g;
            const int rowc = uminc(r0w + rr, N - 1);
            const int deg = min(__shfl(cnt16, rr), 63);
            const int T = deg + 1;               // terms incl. self (slot 0)
            const int* spL = &sbuf[wave][rr][0];
            const int* spG = bucket + (size_t)rowc * BCAP;
            float a[8];
#pragma unroll
            for (int q = 0; q < 8; ++q) a[q] = 0.f;
            const int nSt = (T + 7) >> 3;
            for (int st = 0; st < nSt; ++st) {
                const int base = st * 8;
                int sid[8];
                if (base < 32) {
                    const int4 s4a = *(const int4*)(spL + base);
                    const int4 s4b = *(const int4*)(spL + base + 4);
                    sid[0] = s4a.x; sid[1] = s4a.y; sid[2] = s4a.z; sid[3] = s4a.w;
                    sid[4] = s4b.x; sid[5] = s4b.y; sid[6] = s4b.z; sid[7] = s4b.w;
                } else {
#pragma unroll
                    for (int u = 0; u < 8; ++u)
                        sid[u] = spG[uminc(base + u - 1, BCAP - 1)];
                }
                ushort8v v[8];
#pragma unroll
                for (int u = 0; u < 8; ++u) {
                    const int s = base + u;
                    int src = (s == 0) ? rowc : uminc(sid[u], N - 1);
                    src = (s < T) ? src : N;      // zero row for masked slots
                    v[u] = *(const ushort8v*)(H + (size_t)src * HID + cl * 8);
                }
#pragma unroll
                for (int u = 0; u < 8; ++u)
#pragma unroll
                    for (int q = 0; q < 8; ++q)
                        a[q] += b2f(v[u][q]);
            }
            ushort8v pk;
#pragma unroll
            for (int q = 0; q < 8; ++q) pk[q] = f2b(a[q]);
            const int byt = (rr * 256 + cl * 16) ^ ((rr & 7) << 4);
            *(ushort8v*)(Abase + byt) = pk;
        }
    }

    // ------------------ phase 2: GEMM from LDS ------------------
    const int lr = lane & 15, lk = lane >> 4;
    const int r0 = r0w;
    short8v af[4];
#pragma unroll
    for (int kb = 0; kb < 4; ++kb) {
        const int byt = (lr * 256 + kb * 64 + lk * 16) ^ ((lr & 7) << 4);
        af[kb] = *(const short8v*)(Abase + byt);
    }
    float4v acc[8];
#pragma unroll
    for (int ct = 0; ct < 8; ++ct) {
        float4v c = {0.f, 0.f, 0.f, 0.f};
        const unsigned short* bw = Wt + (size_t)(ct * 16 + lr) * HID + lk * 8;
#pragma unroll
        for (int kb = 0; kb < 4; ++kb) {
            short8v bf = *reinterpret_cast<const short8v*>(bw + kb * 32);
            c = __builtin_amdgcn_mfma_f32_16x16x32_bf16(af[kb], bf, c, 0, 0, 0);
        }
        acc[ct] = c;
    }

#pragma unroll
    for (int ct = 0; ct < 8; ++ct) {
        const int col = ct * 16 + lr;
        const float b = bias[col];
        float s = 0.f, q = 0.f;
#pragma unroll
        for (int j = 0; j < 4; ++j) {
            const int row = r0 + lk * 4 + j;
            if (row < N) {
                const float o = acc[ct][j] + b;
                Out[(size_t)row * HID + col] = f2b(o);
                s += o; q += o * o;
            }
        }
        s += __shfl_xor(s, 16); s += __shfl_xor(s, 32);
        q += __shfl_xor(q, 16); q += __shfl_xor(q, 32);
        if (lk == 0) { atomicAdd(&csum[col], s); atomicAdd(&csq[col], q); }
    }
    __syncthreads();
    if (t < HID) {
        atomicAdd(stats + t, csum[t]);
        atomicAdd(stats + HID + t, csq[t]);
    }
}

// ---- layer2: [fin1 inline -> BN1+ReLU -> GEMM2 -> p2, stats2], 128 rows/block ---
__global__ __launch_bounds__(256) void k_layer2(const unsigned short* __restrict__ A,
                                                const float* __restrict__ st_in,
                                                const float* __restrict__ g_in,
                                                const float* __restrict__ be_in,
                                                const unsigned short* __restrict__ Wt,
                                                const float* __restrict__ bias,
                                                unsigned short* __restrict__ Out,
                                                float* __restrict__ stats, int M) {
    __shared__ float ssS[2 * HID];
    __shared__ float csum[HID], csq[HID];
    const int t = threadIdx.x;
    if (t < HID) { csum[t] = 0.f; csq[t] = 0.f; }
    compute_ss(st_in, g_in, be_in, ssS, M, t);
    __syncthreads();

    const int wave = t >> 6, lane = t & 63;
    const int lr = lane & 15, lk = lane >> 4;

    for (int tt = 0; tt < 2; ++tt) {
        const int r0 = blockIdx.x * 128 + tt * 64 + wave * 16;
        const int arow = r0 + lr;
        const bool rowok = arow < M;

        short8v af[4];
        const unsigned short* ap = A + (size_t)arow * HID + lk * 8;
#pragma unroll
        for (int kb = 0; kb < 4; ++kb) {
            ushort8v raw;
            if (rowok) raw = *reinterpret_cast<const ushort8v*>(ap + kb * 32);
            else       raw = (ushort8v)(unsigned short)0;
            const int k0 = kb * 32 + lk * 8;
            const float4v sc0 = *(const float4v*)&ssS[k0];
            const float4v sc1 = *(const float4v*)&ssS[k0 + 4];
            const float4v sh0 = *(const float4v*)&ssS[HID + k0];
            const float4v sh1 = *(const float4v*)&ssS[HID + k0 + 4];
            ushort8v pk;
#pragma unroll
            for (int j = 0; j < 4; ++j) {
                pk[j]     = f2b(fmaxf(fmaf(b2f(raw[j]),     sc0[j], sh0[j]), 0.f));
                pk[j + 4] = f2b(fmaxf(fmaf(b2f(raw[j + 4]), sc1[j], sh1[j]), 0.f));
            }
            af[kb] = *reinterpret_cast<short8v*>(&pk);
        }

        float4v acc[8];
#pragma unroll
        for (int ct = 0; ct < 8; ++ct) {
            float4v c = {0.f, 0.f, 0.f, 0.f};
            const unsigned short* bw = Wt + (size_t)(ct * 16 + lr) * HID + lk * 8;
#pragma unroll
            for (int kb = 0; kb < 4; ++kb) {
                short8v bf = *reinterpret_cast<const short8v*>(bw + kb * 32);
                c = __builtin_amdgcn_mfma_f32_16x16x32_bf16(af[kb], bf, c, 0, 0, 0);
            }
            acc[ct] = c;
        }

#pragma unroll
        for (int ct = 0; ct < 8; ++ct) {
            const int col = ct * 16 + lr;
            const float b = bias[col];
            float s = 0.f, q = 0.f;
#pragma unroll
            for (int j = 0; j < 4; ++j) {
                const int row = r0 + lk * 4 + j;
                if (row < M) {
                    const float o = acc[ct][j] + b;
                    Out[(size_t)row * HID + col] = f2b(o);
                    s += o; q += o * o;
                }
            }
            s += __shfl_xor(s, 16); s += __shfl_xor(s, 32);
            q += __shfl_xor(q, 16); q += __shfl_xor(q, 32);
            if (lk == 0) { atomicAdd(&csum[col], s); atomicAdd(&csq[col], q); }
        }
    }
    __syncthreads();
    if (t < HID) {
        atomicAdd(stats + t, csum[t]);
        atomicAdd(stats + HID + t, csq[t]);
    }
}

// ---- pool+writeback: vectorized streaming; grid (NGRAPH, 8); LDS reduce ----
__global__ __launch_bounds__(256) void k_pool(const unsigned short* __restrict__ p2,
                                              const float* __restrict__ st,
                                              const float* __restrict__ g,
                                              const float* __restrict__ be,
                                              const int* __restrict__ batch,
                                              int N, float* __restrict__ feats, int it,
                                              unsigned short* __restrict__ hout) {
    __shared__ float ssS[2 * HID];
    __shared__ float red[16 * (HID + 4)];
    const int t = threadIdx.x;
    compute_ss(st, g, be, ssS, N, t);
    __syncthreads();
    const int gph = blockIdx.x;
    int a = 0, b = N;
    while (a < b) { int m = (a + b) >> 1; if (batch[m] < gph) a = m + 1; else b = m; }
    const int lo = a;
    b = N;
    while (a < b) { int m = (a + b) >> 1; if (batch[m] < gph + 1) a = m + 1; else b = m; }
    const int hi = a;
    const int len = hi - lo;
    const int q0 = lo + (int)(((long long)len * blockIdx.y) >> 3);
    const int q1 = lo + (int)(((long long)len * (blockIdx.y + 1)) >> 3);

    const int rl = t >> 4;          // row lane 0..15
    const int cs = t & 15;          // col slice: cols cs*8 .. cs*8+7
    float sc[8], sh[8];
#pragma unroll
    for (int q = 0; q < 8; ++q) { sc[q] = ssS[cs * 8 + q]; sh[q] = ssS[HID + cs * 8 + q]; }

    float acc[8];
#pragma unroll
    for (int q = 0; q < 8; ++q) acc[q] = 0.f;
    for (int r = q0 + rl; r < q1; r += 16) {
        const ushort8v raw = *(const ushort8v*)(p2 + (size_t)r * HID + cs * 8);
        ushort8v pk;
#pragma unroll
        for (int q = 0; q < 8; ++q) {
            const float hv = fmaxf(fmaf(b2f(raw[q]), sc[q], sh[q]), 0.f);
            pk[q] = f2b(hv);
            acc[q] += hv;
        }
        *(ushort8v*)(hout + (size_t)r * HID + cs * 8) = pk;
    }
#pragma unroll
    for (int q = 0; q < 8; ++q) red[rl * (HID + 4) + cs * 8 + q] = acc[q];
    __syncthreads();
    if (t < HID) {
        float s = 0.f;
#pragma unroll
        for (int i = 0; i < 16; ++i) s += red[i * (HID + 4) + t];
        atomicAdd(feats + (size_t)gph * (KIT * HID) + it * HID + t, s);
    }
}

// ---------------- fused head: out = relu(feats@Wh1+bh1)@Wh2 + bh2 ---------------
__global__ __launch_bounds__(KIT * HID) void k_head(const float* __restrict__ feats,
                                                    const float* __restrict__ Wh1,
                                                    const float* __restrict__ bh1,
                                                    const float* __restrict__ Wh2,
                                                    const float* __restrict__ bh2,
                                                    float* __restrict__ out) {
    __shared__ float fr[KIT * HID];
    __shared__ float z1s[KIT * HID];
    const int r = blockIdx.x;
    const int c = threadIdx.x;
    fr[c] = feats[r * (KIT * HID) + c];
    __syncthreads();
    float acc = bh1[c];
    for (int k = 0; k < KIT * HID; ++k) acc = fmaf(fr[k], Wh1[k * (KIT * HID) + c], acc);
    z1s[c] = fmaxf(acc, 0.f);
    __syncthreads();
    if (c < 10) {
        float s = bh2[c];
        for (int k = 0; k < KIT * HID; ++k) s = fmaf(z1s[k], Wh2[k * 10 + c], s);
        out[r * 10 + c] = s;
    }
}

extern "C" void kernel_launch(void* const* d_in, const int* in_sizes, int n_in,
                              void* d_out, int out_size, void* d_ws, size_t ws_size,
                              hipStream_t stream) {
    const float* X   = (const float*)d_in[0];
    const float* W1  = (const float*)d_in[1];
    const float* b1  = (const float*)d_in[2];
    const float* g1  = (const float*)d_in[3];
    const float* be1 = (const float*)d_in[4];
    const float* W2  = (const float*)d_in[5];
    const float* b2  = (const float*)d_in[6];
    const float* g2  = (const float*)d_in[7];
    const float* be2 = (const float*)d_in[8];
    const float* Wh1 = (const float*)d_in[9];
    const float* bh1 = (const float*)d_in[10];
    const float* Wh2 = (const float*)d_in[11];
    const float* bh2 = (const float*)d_in[12];
    const int* esrc  = (const int*)d_in[13];
    const int* edst  = (const int*)d_in[14];
    const int* batch = (const int*)d_in[15];
    float* out = (float*)d_out;

    const int N = in_sizes[0] / HID;
    const int E = in_sizes[13];

    char* w = (char*)d_ws;
    size_t off = 0;
    auto alloc = [&](size_t bytes) {
        void* p = w + off;
        off += (bytes + 255) & ~(size_t)255;
        return p;
    };
    // zero-init block first (cnt, stats, feats contiguous -> ONE memset)
    int*   cnt    = (int*)alloc((size_t)N * 4);
    float* stats  = (float*)alloc((size_t)2 * KIT * 2 * HID * 4);
    float* feats  = (float*)alloc((size_t)NGRAPH * KIT * HID * 4);
    const size_t zero_span = off;
    unsigned short* Xb   = (unsigned short*)alloc((size_t)(N + 1) * HID * 2);  // row N = 0
    unsigned short* h2b  = (unsigned short*)alloc((size_t)(N + 1) * HID * 2);  // row N = 0
    unsigned short* p1b  = (unsigned short*)alloc((size_t)N * HID * 2);
    unsigned short* p2b  = (unsigned short*)alloc((size_t)N * HID * 2);
    unsigned short* Wt1  = (unsigned short*)alloc((size_t)KIT * HID * HID * 2);
    unsigned short* Wt2  = (unsigned short*)alloc((size_t)KIT * HID * HID * 2);
    int*   bucket = (int*)alloc((size_t)N * BCAP * 4);

    hipMemsetAsync(w, 0, zero_span, stream);

    const int rdiv = (N + 7) / 8;
    const int nchunk = (E + BKCHUNK - 1) / BKCHUNK;
    k_bucket<<<nchunk * 8, 256, 0, stream>>>(esrc, edst, cnt, bucket, E, rdiv);

    const int n8 = N * (HID / 8);
    const int nx = (n8 + 255) / 256;
    k_prep<<<nx + 2 * KIT + 1, 256, 0, stream>>>(X, W1, W2, Xb, Wt1, Wt2, h2b, n8, nx, N);

    const int g1grid = (N + 63) / 64;
    const int g2grid = (N + 127) / 128;
    for (int i = 0; i < KIT; ++i) {
        float* st1 = stats + (size_t)(2 * i) * 256;
        float* st2 = stats + (size_t)(2 * i + 1) * 256;
        const unsigned short* hin = (i == 0) ? Xb : h2b;

        k_layer1<<<g1grid, 256, 0, stream>>>(
            hin, cnt, bucket, Wt1 + (size_t)i * HID * HID, b1 + i * HID, p1b, st1, N);
        k_layer2<<<g2grid, 256, 0, stream>>>(
            p1b, st1, g1 + i * HID, be1 + i * HID,
            Wt2 + (size_t)i * HID * HID, b2 + i * HID, p2b, st2, N);
        k_pool<<<dim3(NGRAPH, 8), 256, 0, stream>>>(
            p2b, st2, g2 + i * HID, be2 + i * HID, batch, N, feats, i, h2b);
    }
    k_head<<<NGRAPH, KIT * HID, 0, stream>>>(feats, Wh1, bh1, Wh2, bh2, out);
}